// Round 22
// baseline (457.245 us; speedup 1.0000x reference)
//
#include <hip/hip_runtime.h>
#include <math.h>

#define NN 50000
#define NE 800000
#define IND 256
#define ED 64
#define EMB 128
#define NH 8
#define HD 16

typedef short bf16x8 __attribute__((ext_vector_type(8)));
typedef short bf16x4 __attribute__((ext_vector_type(4)));
typedef float f32x4 __attribute__((ext_vector_type(4)));

#define NPT  (NN / 16)                  // 3125 proj tiles
#define NPB  ((NPT + 3) / 4)            // 782 proj blocks
#define NE4  (NE / 4)                   // 200000 4-edge packets
#define NHB  ((NE4 + 255) / 256)        // 782 hist/bucket blocks
#define NB   ((NN + 511) / 512)         // 98 scan blocks

__device__ __forceinline__ unsigned short rne16(float f) {
    unsigned u = __float_as_uint(f);
    unsigned r = u + 0x7FFFu + ((u >> 16) & 1u);
    return (unsigned short)(r >> 16);
}

// HW packed f32->bf16 (RNE on gfx950): 2 values in 1 VALU op
__device__ __forceinline__ unsigned cvt_pk_bf16(float lo, float hi) {
    unsigned r;
    asm("v_cvt_pk_bf16_f32 %0, %1, %2" : "=v"(r) : "v"(lo), "v"(hi));
    return r;
}

__device__ __forceinline__ float bf2f(unsigned short s) {
    return __uint_as_float(((unsigned)s) << 16);
}

// mish(v) = v * (1 - 2/(w^2 + 2w + 2)), w = e^v.  No clamp needed.
__device__ __forceinline__ float mishf(float v) {
    float w = __expf(v);
    float p = fmaf(w, w, w + w);
    float t = fmaf(-2.f, __builtin_amdgcn_rcpf(p + 2.f), 1.f);
    return v * t;
}

// ------- fused: MFMA node projection + rcv histogram (ordinal out) ---------
__global__ __launch_bounds__(256) void k_proj_hist(
    const float* __restrict__ X, const float* __restrict__ W,
    const float* __restrict__ b, short* __restrict__ hbf,
    const int* __restrict__ rcv, int* __restrict__ cnt,
    int* __restrict__ ord) {
    if (blockIdx.x >= NPB) {            // histogram: 4 edges/thread, save ordinal
        int e0 = ((blockIdx.x - NPB) * 256 + threadIdx.x) * 4;
        if (e0 + 3 < NE) {
            int4 r4 = *(const int4*)&rcv[e0];
            int o0 = atomicAdd(&cnt[r4.x], 1);
            int o1 = atomicAdd(&cnt[r4.y], 1);
            int o2 = atomicAdd(&cnt[r4.z], 1);
            int o3 = atomicAdd(&cnt[r4.w], 1);
            *(int4*)&ord[e0] = make_int4(o0, o1, o2, o3);
        }
        return;
    }
    __shared__ short BHs[IND * EMB];    // 64 KB bf16 fragment tile
    for (int idx = threadIdx.x * 4; idx < IND * EMB; idx += 256 * 4) {
        float4 wv = *(const float4*)&W[idx];
        int k = idx >> 7;
        int col = idx & 127;
        int kk8 = k >> 5, qq = (k & 31) >> 3, j = k & 7;
        float wf[4] = {wv.x, wv.y, wv.z, wv.w};
        #pragma unroll
        for (int i = 0; i < 4; ++i) {
            int cc = (col + i) & 7, lc = (col + i) >> 3;
            int lane = (qq << 4) | lc;
            BHs[(((cc << 3) | kk8) * 64 + lane) * 8 + j] = (short)rne16(wf[i]);
        }
    }
    __syncthreads();

    const int l = threadIdx.x & 63;
    const int lanecol = l & 15;
    const int q = l >> 4;
    const int wid = (blockIdx.x << 2) + (threadIdx.x >> 6);
    const int nW = NPB << 2;

    float4 bv0 = *(const float4*)&b[lanecol * 8];
    float4 bv1 = *(const float4*)&b[lanecol * 8 + 4];
    float wb[8] = {bv0.x, bv0.y, bv0.z, bv0.w, bv1.x, bv1.y, bv1.z, bv1.w};

    for (int tIdx = wid; tIdx < NPT; tIdx += nW) {
        const int n0 = tIdx * 16;
        f32x4 acc[8];
        #pragma unroll
        for (int c = 0; c < 8; ++c) acc[c] = (f32x4){0.f, 0.f, 0.f, 0.f};
        #pragma unroll
        for (int kk8 = 0; kk8 < 8; ++kk8) {
            const float* ar = X + (size_t)(n0 + lanecol) * IND + kk8 * 32 + q * 8;
            float4 a0 = *(const float4*)ar;
            float4 a1 = *(const float4*)(ar + 4);
            int4 pa;
            pa.x = (int)cvt_pk_bf16(a0.x, a0.y);
            pa.y = (int)cvt_pk_bf16(a0.z, a0.w);
            pa.z = (int)cvt_pk_bf16(a1.x, a1.y);
            pa.w = (int)cvt_pk_bf16(a1.z, a1.w);
            bf16x8 ahi = *(bf16x8*)&pa;
            #pragma unroll
            for (int c = 0; c < 8; ++c) {
                bf16x8 bh = *(bf16x8*)&BHs[(((c << 3) | kk8) * 64 + l) * 8];
                acc[c] = __builtin_amdgcn_mfma_f32_16x16x32_bf16(ahi, bh, acc[c], 0, 0, 0);
            }
        }
        #pragma unroll
        for (int r = 0; r < 4; ++r) {
            const int node = n0 + (q << 2) + r;
            int4 po;
            po.x = (int)cvt_pk_bf16(acc[0][r] + wb[0], acc[1][r] + wb[1]);
            po.y = (int)cvt_pk_bf16(acc[2][r] + wb[2], acc[3][r] + wb[3]);
            po.z = (int)cvt_pk_bf16(acc[4][r] + wb[4], acc[5][r] + wb[5]);
            po.w = (int)cvt_pk_bf16(acc[6][r] + wb[6], acc[7][r] + wb[7]);
            *(int4*)(hbf + (size_t)node * EMB + lanecol * 8) = po;
        }
    }
}

// ---------------- CSR build: per-block scan, merged fixup ------------------
__global__ __launch_bounds__(512) void k_part(const int* __restrict__ cnt,
                                              int* __restrict__ rowptr,
                                              int* __restrict__ part) {
    __shared__ int sm[512];
    const int t = threadIdx.x;
    const int idx = blockIdx.x * 512 + t;
    int v = (idx < NN) ? cnt[idx] : 0;
    sm[t] = v;
    __syncthreads();
    #pragma unroll
    for (int off = 1; off < 512; off <<= 1) {
        int y = (t >= off) ? sm[t - off] : 0;
        __syncthreads();
        sm[t] += y;
        __syncthreads();
    }
    if (idx < NN) rowptr[idx] = sm[t] - v;
    if (t == 511) part[blockIdx.x] = sm[511];
}

__global__ __launch_bounds__(512) void k_fix2(const int* __restrict__ part,
                                              int* __restrict__ rowptr) {
    __shared__ int sm[128];
    const int t = threadIdx.x;
    if (t < 128) sm[t] = (t < NB) ? part[t] : 0;
    __syncthreads();
    #pragma unroll
    for (int off = 1; off < 128; off <<= 1) {
        int y = 0;
        if (t < 128 && t >= off) y = sm[t - off];
        __syncthreads();
        if (t < 128) sm[t] += y;
        __syncthreads();
    }
    const int boff = (blockIdx.x > 0) ? sm[blockIdx.x - 1] : 0;
    const int idx = blockIdx.x * 512 + t;
    if (idx < NN) rowptr[idx] += boff;
    if (blockIdx.x == 0 && t == 0) rowptr[NN] = NE;
}

// -------- bucket: ATOMIC-FREE scatter via precomputed ordinal --------------
__global__ __launch_bounds__(256) void k_bucket(
    const int* __restrict__ snd, const int* __restrict__ rcv,
    const int* __restrict__ ord, const int* __restrict__ rowptr,
    int2* __restrict__ rec) {
    int e0 = (blockIdx.x * 256 + threadIdx.x) * 4;
    if (e0 + 3 < NE) {
        int4 s4 = *(const int4*)&snd[e0];
        int4 r4 = *(const int4*)&rcv[e0];
        int4 o4 = *(const int4*)&ord[e0];
        rec[rowptr[r4.x] + o4.x] = make_int2(e0,     s4.x | (r4.x << 16));
        rec[rowptr[r4.y] + o4.y] = make_int2(e0 + 1, s4.y | (r4.y << 16));
        rec[rowptr[r4.z] + o4.z] = make_int2(e0 + 2, s4.z | (r4.z << 16));
        rec[rowptr[r4.w] + o4.w] = make_int2(e0 + 3, s4.w | (r4.w << 16));
    }
}

// ---------- fused edge pass, CSR order: split-half gathers, 8 waves/SIMD ---
__global__ __launch_bounds__(256, 8) void k_edge_attn(
    const float* __restrict__ EF, const float* __restrict__ We,
    const float* __restrict__ Web, const float* __restrict__ Av,
    const short* __restrict__ hbf, const int2* __restrict__ rec,
    unsigned short* __restrict__ exbf) {
    __shared__ short BHs[ED * EMB];     // 16 KB bf16 fragment tile
    __shared__ float2 WA[144];          // (Web, Av) pairs, stride-9 padded
    for (int idx = threadIdx.x * 4; idx < ED * EMB; idx += 256 * 4) {
        float4 wv = *(const float4*)&We[idx];
        int k = idx >> 7;
        int col = idx & 127;
        int kk = k >> 5, qq = (k & 31) >> 3, j = k & 7;
        float wf[4] = {wv.x, wv.y, wv.z, wv.w};
        #pragma unroll
        for (int i = 0; i < 4; ++i) {
            int cc = (col + i) & 7, lc = (col + i) >> 3;
            int lane = (qq << 4) | lc;
            BHs[(((cc << 1) | kk) * 64 + lane) * 8 + j] = (short)rne16(wf[i]);
        }
    }
    if (threadIdx.x < 128) {
        int c = threadIdx.x & 7, lc = threadIdx.x >> 3;
        WA[lc * 9 + c] = make_float2(Web[threadIdx.x], Av[threadIdx.x]);
    }
    __syncthreads();

    const int l = threadIdx.x & 63;
    const int lanecol = l & 15;
    const int q = l >> 4;
    const int wid = (blockIdx.x << 2) + (threadIdx.x >> 6);
    const int nW = gridDim.x << 2;
    const int NT = NE / 16;

    for (int tIdx = wid; tIdx < NT; tIdx += nW) {
        int2 rc = rec[(size_t)tIdx * 16 + lanecol];

        unsigned u0 = (unsigned)__shfl(rc.y, (q << 2) + 0, 16);
        unsigned u1 = (unsigned)__shfl(rc.y, (q << 2) + 1, 16);
        unsigned u2 = (unsigned)__shfl(rc.y, (q << 2) + 2, 16);
        unsigned u3 = (unsigned)__shfl(rc.y, (q << 2) + 3, 16);

        bf16x4 hs0a = *(const bf16x4*)(hbf + (size_t)(u0 & 0xFFFFu) * EMB + lanecol * 8);
        bf16x4 hr0a = *(const bf16x4*)(hbf + (size_t)(u0 >> 16) * EMB + lanecol * 8);
        bf16x4 hs1a = *(const bf16x4*)(hbf + (size_t)(u1 & 0xFFFFu) * EMB + lanecol * 8);
        bf16x4 hr1a = *(const bf16x4*)(hbf + (size_t)(u1 >> 16) * EMB + lanecol * 8);
        bf16x4 hs2a = *(const bf16x4*)(hbf + (size_t)(u2 & 0xFFFFu) * EMB + lanecol * 8);
        bf16x4 hr2a = *(const bf16x4*)(hbf + (size_t)(u2 >> 16) * EMB + lanecol * 8);
        bf16x4 hs3a = *(const bf16x4*)(hbf + (size_t)(u3 & 0xFFFFu) * EMB + lanecol * 8);
        bf16x4 hr3a = *(const bf16x4*)(hbf + (size_t)(u3 >> 16) * EMB + lanecol * 8);

        const float* ar = EF + (size_t)rc.x * ED + q * 8;
        bf16x8 ahi0, ahi1;
        {
            float4 a0 = *(const float4*)ar;
            float4 a1 = *(const float4*)(ar + 4);
            float4 a2 = *(const float4*)(ar + 32);
            float4 a3 = *(const float4*)(ar + 36);
            int4 p0, p1;
            p0.x = (int)cvt_pk_bf16(a0.x, a0.y);
            p0.y = (int)cvt_pk_bf16(a0.z, a0.w);
            p0.z = (int)cvt_pk_bf16(a1.x, a1.y);
            p0.w = (int)cvt_pk_bf16(a1.z, a1.w);
            p1.x = (int)cvt_pk_bf16(a2.x, a2.y);
            p1.y = (int)cvt_pk_bf16(a2.z, a2.w);
            p1.z = (int)cvt_pk_bf16(a3.x, a3.y);
            p1.w = (int)cvt_pk_bf16(a3.z, a3.w);
            ahi0 = *(bf16x8*)&p0;
            ahi1 = *(bf16x8*)&p1;
        }

        float pp[4] = {0.f, 0.f, 0.f, 0.f};
        #pragma unroll
        for (int c = 0; c < 4; ++c) {
            float2 wa = WA[lanecol * 9 + c];
            bf16x8 b0 = *(bf16x8*)&BHs[(((c << 1) | 0) * 64 + l) * 8];
            bf16x8 b1 = *(bf16x8*)&BHs[(((c << 1) | 1) * 64 + l) * 8];
            f32x4 a4 = (f32x4){wa.x, wa.x, wa.x, wa.x};
            a4 = __builtin_amdgcn_mfma_f32_16x16x32_bf16(ahi0, b0, a4, 0, 0, 0);
            a4 = __builtin_amdgcn_mfma_f32_16x16x32_bf16(ahi1, b1, a4, 0, 0, 0);
            pp[0] = fmaf(mishf(a4[0] + bf2f((unsigned short)hs0a[c]) + bf2f((unsigned short)hr0a[c])), wa.y, pp[0]);
            pp[1] = fmaf(mishf(a4[1] + bf2f((unsigned short)hs1a[c]) + bf2f((unsigned short)hr1a[c])), wa.y, pp[1]);
            pp[2] = fmaf(mishf(a4[2] + bf2f((unsigned short)hs2a[c]) + bf2f((unsigned short)hr2a[c])), wa.y, pp[2]);
            pp[3] = fmaf(mishf(a4[3] + bf2f((unsigned short)hs3a[c]) + bf2f((unsigned short)hr3a[c])), wa.y, pp[3]);
        }

        bf16x4 hs0b = *(const bf16x4*)(hbf + (size_t)(u0 & 0xFFFFu) * EMB + lanecol * 8 + 4);
        bf16x4 hr0b = *(const bf16x4*)(hbf + (size_t)(u0 >> 16) * EMB + lanecol * 8 + 4);
        bf16x4 hs1b = *(const bf16x4*)(hbf + (size_t)(u1 & 0xFFFFu) * EMB + lanecol * 8 + 4);
        bf16x4 hr1b = *(const bf16x4*)(hbf + (size_t)(u1 >> 16) * EMB + lanecol * 8 + 4);
        bf16x4 hs2b = *(const bf16x4*)(hbf + (size_t)(u2 & 0xFFFFu) * EMB + lanecol * 8 + 4);
        bf16x4 hr2b = *(const bf16x4*)(hbf + (size_t)(u2 >> 16) * EMB + lanecol * 8 + 4);
        bf16x4 hs3b = *(const bf16x4*)(hbf + (size_t)(u3 & 0xFFFFu) * EMB + lanecol * 8 + 4);
        bf16x4 hr3b = *(const bf16x4*)(hbf + (size_t)(u3 >> 16) * EMB + lanecol * 8 + 4);

        #pragma unroll
        for (int c = 4; c < 8; ++c) {
            float2 wa = WA[lanecol * 9 + c];
            bf16x8 b0 = *(bf16x8*)&BHs[(((c << 1) | 0) * 64 + l) * 8];
            bf16x8 b1 = *(bf16x8*)&BHs[(((c << 1) | 1) * 64 + l) * 8];
            f32x4 a4 = (f32x4){wa.x, wa.x, wa.x, wa.x};
            a4 = __builtin_amdgcn_mfma_f32_16x16x32_bf16(ahi0, b0, a4, 0, 0, 0);
            a4 = __builtin_amdgcn_mfma_f32_16x16x32_bf16(ahi1, b1, a4, 0, 0, 0);
            pp[0] = fmaf(mishf(a4[0] + bf2f((unsigned short)hs0b[c - 4]) + bf2f((unsigned short)hr0b[c - 4])), wa.y, pp[0]);
            pp[1] = fmaf(mishf(a4[1] + bf2f((unsigned short)hs1b[c - 4]) + bf2f((unsigned short)hr1b[c - 4])), wa.y, pp[1]);
            pp[2] = fmaf(mishf(a4[2] + bf2f((unsigned short)hs2b[c - 4]) + bf2f((unsigned short)hr2b[c - 4])), wa.y, pp[2]);
            pp[3] = fmaf(mishf(a4[3] + bf2f((unsigned short)hs3b[c - 4]) + bf2f((unsigned short)hr3b[c - 4])), wa.y, pp[3]);
        }

        #pragma unroll
        for (int r = 0; r < 4; ++r) {
            float pr = pp[r];
            pr += __shfl_xor(pr, 1, 16);
            const size_t pos = (size_t)tIdx * 16 + (q << 2) + r;
            if ((lanecol & 1) == 0)
                exbf[pos * NH + (lanecol >> 1)] = rne16(__expf(pr));
        }
    }
}

// --------- segmented aggregation: 16-deep gather burst + 8/4/1 tails -------
__global__ __launch_bounds__(256) void k_agg(
    const short* __restrict__ hbf, const int2* __restrict__ rec,
    const unsigned short* __restrict__ exbf, const int* __restrict__ rowptr,
    float* __restrict__ out) {
    const int l = threadIdx.x & 63;
    const int node = blockIdx.x * 4 + (threadIdx.x >> 6);
    if (node >= NN) return;
    const int beg = rowptr[node], end = rowptr[node + 1];
    const int h = l >> 3;
    float a0 = 0.f, a1 = 0.f, den = 0.f;
    int j = beg;
    for (; j + 16 <= end; j += 16) {
        int s[16];
        float ex[16];
        unsigned hv[16];
        #pragma unroll
        for (int i = 0; i < 16; ++i) s[i] = rec[j + i].y & 0xFFFF;
        #pragma unroll
        for (int i = 0; i < 16; ++i) ex[i] = bf2f(exbf[(size_t)(j + i) * NH + h]);
        #pragma unroll
        for (int i = 0; i < 16; ++i)
            hv[i] = *(const unsigned*)(hbf + (size_t)s[i] * EMB + 2 * l);
        #pragma unroll
        for (int i = 0; i < 16; ++i) {
            a0 = fmaf(ex[i], bf2f((unsigned short)(hv[i] & 0xFFFF)), a0);
            a1 = fmaf(ex[i], bf2f((unsigned short)(hv[i] >> 16)), a1);
            den += ex[i];
        }
    }
    if (j + 8 <= end) {
        int s[8];
        float ex[8];
        unsigned hv[8];
        #pragma unroll
        for (int i = 0; i < 8; ++i) s[i] = rec[j + i].y & 0xFFFF;
        #pragma unroll
        for (int i = 0; i < 8; ++i) ex[i] = bf2f(exbf[(size_t)(j + i) * NH + h]);
        #pragma unroll
        for (int i = 0; i < 8; ++i)
            hv[i] = *(const unsigned*)(hbf + (size_t)s[i] * EMB + 2 * l);
        #pragma unroll
        for (int i = 0; i < 8; ++i) {
            a0 = fmaf(ex[i], bf2f((unsigned short)(hv[i] & 0xFFFF)), a0);
            a1 = fmaf(ex[i], bf2f((unsigned short)(hv[i] >> 16)), a1);
            den += ex[i];
        }
        j += 8;
    }
    if (j + 4 <= end) {
        int s[4];
        float ex[4];
        unsigned hv[4];
        #pragma unroll
        for (int i = 0; i < 4; ++i) s[i] = rec[j + i].y & 0xFFFF;
        #pragma unroll
        for (int i = 0; i < 4; ++i) ex[i] = bf2f(exbf[(size_t)(j + i) * NH + h]);
        #pragma unroll
        for (int i = 0; i < 4; ++i)
            hv[i] = *(const unsigned*)(hbf + (size_t)s[i] * EMB + 2 * l);
        #pragma unroll
        for (int i = 0; i < 4; ++i) {
            a0 = fmaf(ex[i], bf2f((unsigned short)(hv[i] & 0xFFFF)), a0);
            a1 = fmaf(ex[i], bf2f((unsigned short)(hv[i] >> 16)), a1);
            den += ex[i];
        }
        j += 4;
    }
    for (; j < end; ++j) {
        float ex = bf2f(exbf[(size_t)j * NH + h]);
        unsigned hv = *(const unsigned*)(hbf + (size_t)(rec[j].y & 0xFFFF) * EMB + 2 * l);
        a0 = fmaf(ex, bf2f((unsigned short)(hv & 0xFFFF)), a0);
        a1 = fmaf(ex, bf2f((unsigned short)(hv >> 16)), a1);
        den += ex;
    }
    float rd = (end > beg) ? __builtin_amdgcn_rcpf(den) : 0.f;
    float2 o;
    o.x = a0 * rd;
    o.y = a1 * rd;
    *(float2*)&out[(size_t)node * EMB + 2 * l] = o;
}

extern "C" void kernel_launch(void* const* d_in, const int* in_sizes, int n_in,
                              void* d_out, int out_size, void* d_ws, size_t ws_size,
                              hipStream_t stream) {
    const float* X   = (const float*)d_in[0];
    const float* EF  = (const float*)d_in[1];
    const float* W   = (const float*)d_in[2];
    const float* Wb  = (const float*)d_in[3];
    const float* We  = (const float*)d_in[4];
    const float* Web = (const float*)d_in[5];
    const float* Av  = (const float*)d_in[6];
    const int* snd   = (const int*)d_in[7];
    const int* rcv   = (const int*)d_in[8];
    float* out = (float*)d_out;

    char* ws = (char*)d_ws;
    size_t off = 0;
    unsigned short* exbf = (unsigned short*)(ws + off); off += (size_t)NE * NH * 2; // 12.8 MB
    int2* rec     = (int2*)(ws + off);  off += (size_t)NE * 8;         // 6.4 MB
    int* ord      = (int*)(ws + off);   off += (size_t)NE * 4;         // 3.2 MB
    int* rowptr   = (int*)(ws + off);   off += (size_t)(NN + 1) * 4;
    int* cnt      = (int*)(ws + off);   off += (size_t)NN * 4;
    int* part     = (int*)(ws + off);   off += 512;
    short* hbf    = (short*)(ws + off); off += (size_t)NN * EMB * 2;   // 12.8 MB

    hipMemsetAsync(cnt, 0, (size_t)NN * sizeof(int), stream);
    k_proj_hist<<<NPB + NHB, 256, 0, stream>>>(X, W, Wb, hbf, rcv, cnt, ord);
    k_part<<<NB, 512, 0, stream>>>(cnt, rowptr, part);
    k_fix2<<<NB, 512, 0, stream>>>(part, rowptr);
    k_bucket<<<NHB, 256, 0, stream>>>(snd, rcv, ord, rowptr, rec);
    k_edge_attn<<<2048, 256, 0, stream>>>(EF, We, Web, Av, hbf, rec, exbf);
    k_agg<<<(NN + 3) / 4, 256, 0, stream>>>(hbf, rec, exbf, rowptr, out);
}

// Round 23
// 218.767 us; speedup vs baseline: 2.0901x; 2.0901x over previous
//
#include <hip/hip_runtime.h>
#include <math.h>

#define NN 50000
#define NE 800000
#define IND 256
#define ED 64
#define EMB 128
#define NH 8
#define HD 16

typedef short bf16x8 __attribute__((ext_vector_type(8)));
typedef short bf16x4 __attribute__((ext_vector_type(4)));
typedef float f32x4 __attribute__((ext_vector_type(4)));

#define NPT  (NN / 16)                  // 3125 proj tiles
#define NPB  ((NPT + 3) / 4)            // 782 proj blocks
#define NE4  (NE / 4)                   // 200000 4-edge packets
#define NHB  ((NE4 + 255) / 256)        // 782 hist/bucket blocks
#define NB   ((NN + 511) / 512)         // 98 scan blocks

__device__ __forceinline__ unsigned short rne16(float f) {
    unsigned u = __float_as_uint(f);
    unsigned r = u + 0x7FFFu + ((u >> 16) & 1u);
    return (unsigned short)(r >> 16);
}

// HW packed f32->bf16 (RNE on gfx950): 2 values in 1 VALU op
__device__ __forceinline__ unsigned cvt_pk_bf16(float lo, float hi) {
    unsigned r;
    asm("v_cvt_pk_bf16_f32 %0, %1, %2" : "=v"(r) : "v"(lo), "v"(hi));
    return r;
}

__device__ __forceinline__ float bf2f(unsigned short s) {
    return __uint_as_float(((unsigned)s) << 16);
}

// mish(v) = v * (1 - 2/(w^2 + 2w + 2)), w = e^v.  No clamp needed.
__device__ __forceinline__ float mishf(float v) {
    float w = __expf(v);
    float p = fmaf(w, w, w + w);
    float t = fmaf(-2.f, __builtin_amdgcn_rcpf(p + 2.f), 1.f);
    return v * t;
}

// ------- fused: MFMA node projection + rcv histogram (ordinal out) ---------
__global__ __launch_bounds__(256) void k_proj_hist(
    const float* __restrict__ X, const float* __restrict__ W,
    const float* __restrict__ b, short* __restrict__ hbf,
    const int* __restrict__ rcv, int* __restrict__ cnt,
    int* __restrict__ ord) {
    if (blockIdx.x >= NPB) {            // histogram: 4 edges/thread, save ordinal
        int e0 = ((blockIdx.x - NPB) * 256 + threadIdx.x) * 4;
        if (e0 + 3 < NE) {
            int4 r4 = *(const int4*)&rcv[e0];
            int o0 = atomicAdd(&cnt[r4.x], 1);
            int o1 = atomicAdd(&cnt[r4.y], 1);
            int o2 = atomicAdd(&cnt[r4.z], 1);
            int o3 = atomicAdd(&cnt[r4.w], 1);
            *(int4*)&ord[e0] = make_int4(o0, o1, o2, o3);
        }
        return;
    }
    __shared__ short BHs[IND * EMB];    // 64 KB bf16 fragment tile
    for (int idx = threadIdx.x * 4; idx < IND * EMB; idx += 256 * 4) {
        float4 wv = *(const float4*)&W[idx];
        int k = idx >> 7;
        int col = idx & 127;
        int kk8 = k >> 5, qq = (k & 31) >> 3, j = k & 7;
        float wf[4] = {wv.x, wv.y, wv.z, wv.w};
        #pragma unroll
        for (int i = 0; i < 4; ++i) {
            int cc = (col + i) & 7, lc = (col + i) >> 3;
            int lane = (qq << 4) | lc;
            BHs[(((cc << 3) | kk8) * 64 + lane) * 8 + j] = (short)rne16(wf[i]);
        }
    }
    __syncthreads();

    const int l = threadIdx.x & 63;
    const int lanecol = l & 15;
    const int q = l >> 4;
    const int wid = (blockIdx.x << 2) + (threadIdx.x >> 6);
    const int nW = NPB << 2;

    float4 bv0 = *(const float4*)&b[lanecol * 8];
    float4 bv1 = *(const float4*)&b[lanecol * 8 + 4];
    float wb[8] = {bv0.x, bv0.y, bv0.z, bv0.w, bv1.x, bv1.y, bv1.z, bv1.w};

    for (int tIdx = wid; tIdx < NPT; tIdx += nW) {
        const int n0 = tIdx * 16;
        f32x4 acc[8];
        #pragma unroll
        for (int c = 0; c < 8; ++c) acc[c] = (f32x4){0.f, 0.f, 0.f, 0.f};
        #pragma unroll
        for (int kk8 = 0; kk8 < 8; ++kk8) {
            const float* ar = X + (size_t)(n0 + lanecol) * IND + kk8 * 32 + q * 8;
            float4 a0 = *(const float4*)ar;
            float4 a1 = *(const float4*)(ar + 4);
            int4 pa;
            pa.x = (int)cvt_pk_bf16(a0.x, a0.y);
            pa.y = (int)cvt_pk_bf16(a0.z, a0.w);
            pa.z = (int)cvt_pk_bf16(a1.x, a1.y);
            pa.w = (int)cvt_pk_bf16(a1.z, a1.w);
            bf16x8 ahi = *(bf16x8*)&pa;
            #pragma unroll
            for (int c = 0; c < 8; ++c) {
                bf16x8 bh = *(bf16x8*)&BHs[(((c << 3) | kk8) * 64 + l) * 8];
                acc[c] = __builtin_amdgcn_mfma_f32_16x16x32_bf16(ahi, bh, acc[c], 0, 0, 0);
            }
        }
        #pragma unroll
        for (int r = 0; r < 4; ++r) {
            const int node = n0 + (q << 2) + r;
            int4 po;
            po.x = (int)cvt_pk_bf16(acc[0][r] + wb[0], acc[1][r] + wb[1]);
            po.y = (int)cvt_pk_bf16(acc[2][r] + wb[2], acc[3][r] + wb[3]);
            po.z = (int)cvt_pk_bf16(acc[4][r] + wb[4], acc[5][r] + wb[5]);
            po.w = (int)cvt_pk_bf16(acc[6][r] + wb[6], acc[7][r] + wb[7]);
            *(int4*)(hbf + (size_t)node * EMB + lanecol * 8) = po;
        }
    }
}

// ---------------- CSR build: per-block scan, merged fixup ------------------
__global__ __launch_bounds__(512) void k_part(const int* __restrict__ cnt,
                                              int* __restrict__ rowptr,
                                              int* __restrict__ part) {
    __shared__ int sm[512];
    const int t = threadIdx.x;
    const int idx = blockIdx.x * 512 + t;
    int v = (idx < NN) ? cnt[idx] : 0;
    sm[t] = v;
    __syncthreads();
    #pragma unroll
    for (int off = 1; off < 512; off <<= 1) {
        int y = (t >= off) ? sm[t - off] : 0;
        __syncthreads();
        sm[t] += y;
        __syncthreads();
    }
    if (idx < NN) rowptr[idx] = sm[t] - v;
    if (t == 511) part[blockIdx.x] = sm[511];
}

__global__ __launch_bounds__(512) void k_fix2(const int* __restrict__ part,
                                              int* __restrict__ rowptr) {
    __shared__ int sm[128];
    const int t = threadIdx.x;
    if (t < 128) sm[t] = (t < NB) ? part[t] : 0;
    __syncthreads();
    #pragma unroll
    for (int off = 1; off < 128; off <<= 1) {
        int y = 0;
        if (t < 128 && t >= off) y = sm[t - off];
        __syncthreads();
        if (t < 128) sm[t] += y;
        __syncthreads();
    }
    const int boff = (blockIdx.x > 0) ? sm[blockIdx.x - 1] : 0;
    const int idx = blockIdx.x * 512 + t;
    if (idx < NN) rowptr[idx] += boff;
    if (blockIdx.x == 0 && t == 0) rowptr[NN] = NE;
}

// -------- bucket: ATOMIC-FREE scatter via precomputed ordinal --------------
__global__ __launch_bounds__(256) void k_bucket(
    const int* __restrict__ snd, const int* __restrict__ rcv,
    const int* __restrict__ ord, const int* __restrict__ rowptr,
    int2* __restrict__ rec) {
    int e0 = (blockIdx.x * 256 + threadIdx.x) * 4;
    if (e0 + 3 < NE) {
        int4 s4 = *(const int4*)&snd[e0];
        int4 r4 = *(const int4*)&rcv[e0];
        int4 o4 = *(const int4*)&ord[e0];
        rec[rowptr[r4.x] + o4.x] = make_int2(e0,     s4.x | (r4.x << 16));
        rec[rowptr[r4.y] + o4.y] = make_int2(e0 + 1, s4.y | (r4.y << 16));
        rec[rowptr[r4.z] + o4.z] = make_int2(e0 + 2, s4.z | (r4.z << 16));
        rec[rowptr[r4.w] + o4.w] = make_int2(e0 + 3, s4.w | (r4.w << 16));
    }
}

// ---------- fused edge pass, CSR order: split-half gathers -----------------
__global__ __launch_bounds__(256) void k_edge_attn(
    const float* __restrict__ EF, const float* __restrict__ We,
    const float* __restrict__ Web, const float* __restrict__ Av,
    const short* __restrict__ hbf, const int2* __restrict__ rec,
    unsigned short* __restrict__ exbf) {
    __shared__ short BHs[ED * EMB];     // 16 KB bf16 fragment tile
    __shared__ float2 WA[144];          // (Web, Av) pairs, stride-9 padded
    for (int idx = threadIdx.x * 4; idx < ED * EMB; idx += 256 * 4) {
        float4 wv = *(const float4*)&We[idx];
        int k = idx >> 7;
        int col = idx & 127;
        int kk = k >> 5, qq = (k & 31) >> 3, j = k & 7;
        float wf[4] = {wv.x, wv.y, wv.z, wv.w};
        #pragma unroll
        for (int i = 0; i < 4; ++i) {
            int cc = (col + i) & 7, lc = (col + i) >> 3;
            int lane = (qq << 4) | lc;
            BHs[(((cc << 1) | kk) * 64 + lane) * 8 + j] = (short)rne16(wf[i]);
        }
    }
    if (threadIdx.x < 128) {
        int c = threadIdx.x & 7, lc = threadIdx.x >> 3;
        WA[lc * 9 + c] = make_float2(Web[threadIdx.x], Av[threadIdx.x]);
    }
    __syncthreads();

    const int l = threadIdx.x & 63;
    const int lanecol = l & 15;
    const int q = l >> 4;
    const int wid = (blockIdx.x << 2) + (threadIdx.x >> 6);
    const int nW = gridDim.x << 2;
    const int NT = NE / 16;

    for (int tIdx = wid; tIdx < NT; tIdx += nW) {
        int2 rc = rec[(size_t)tIdx * 16 + lanecol];

        unsigned u0 = (unsigned)__shfl(rc.y, (q << 2) + 0, 16);
        unsigned u1 = (unsigned)__shfl(rc.y, (q << 2) + 1, 16);
        unsigned u2 = (unsigned)__shfl(rc.y, (q << 2) + 2, 16);
        unsigned u3 = (unsigned)__shfl(rc.y, (q << 2) + 3, 16);

        bf16x4 hs0a = *(const bf16x4*)(hbf + (size_t)(u0 & 0xFFFFu) * EMB + lanecol * 8);
        bf16x4 hr0a = *(const bf16x4*)(hbf + (size_t)(u0 >> 16) * EMB + lanecol * 8);
        bf16x4 hs1a = *(const bf16x4*)(hbf + (size_t)(u1 & 0xFFFFu) * EMB + lanecol * 8);
        bf16x4 hr1a = *(const bf16x4*)(hbf + (size_t)(u1 >> 16) * EMB + lanecol * 8);
        bf16x4 hs2a = *(const bf16x4*)(hbf + (size_t)(u2 & 0xFFFFu) * EMB + lanecol * 8);
        bf16x4 hr2a = *(const bf16x4*)(hbf + (size_t)(u2 >> 16) * EMB + lanecol * 8);
        bf16x4 hs3a = *(const bf16x4*)(hbf + (size_t)(u3 & 0xFFFFu) * EMB + lanecol * 8);
        bf16x4 hr3a = *(const bf16x4*)(hbf + (size_t)(u3 >> 16) * EMB + lanecol * 8);

        const float* ar = EF + (size_t)rc.x * ED + q * 8;
        bf16x8 ahi0, ahi1;
        {
            float4 a0 = *(const float4*)ar;
            float4 a1 = *(const float4*)(ar + 4);
            float4 a2 = *(const float4*)(ar + 32);
            float4 a3 = *(const float4*)(ar + 36);
            int4 p0, p1;
            p0.x = (int)cvt_pk_bf16(a0.x, a0.y);
            p0.y = (int)cvt_pk_bf16(a0.z, a0.w);
            p0.z = (int)cvt_pk_bf16(a1.x, a1.y);
            p0.w = (int)cvt_pk_bf16(a1.z, a1.w);
            p1.x = (int)cvt_pk_bf16(a2.x, a2.y);
            p1.y = (int)cvt_pk_bf16(a2.z, a2.w);
            p1.z = (int)cvt_pk_bf16(a3.x, a3.y);
            p1.w = (int)cvt_pk_bf16(a3.z, a3.w);
            ahi0 = *(bf16x8*)&p0;
            ahi1 = *(bf16x8*)&p1;
        }

        float pp[4] = {0.f, 0.f, 0.f, 0.f};
        #pragma unroll
        for (int c = 0; c < 4; ++c) {
            float2 wa = WA[lanecol * 9 + c];
            bf16x8 b0 = *(bf16x8*)&BHs[(((c << 1) | 0) * 64 + l) * 8];
            bf16x8 b1 = *(bf16x8*)&BHs[(((c << 1) | 1) * 64 + l) * 8];
            f32x4 a4 = (f32x4){wa.x, wa.x, wa.x, wa.x};
            a4 = __builtin_amdgcn_mfma_f32_16x16x32_bf16(ahi0, b0, a4, 0, 0, 0);
            a4 = __builtin_amdgcn_mfma_f32_16x16x32_bf16(ahi1, b1, a4, 0, 0, 0);
            pp[0] = fmaf(mishf(a4[0] + bf2f((unsigned short)hs0a[c]) + bf2f((unsigned short)hr0a[c])), wa.y, pp[0]);
            pp[1] = fmaf(mishf(a4[1] + bf2f((unsigned short)hs1a[c]) + bf2f((unsigned short)hr1a[c])), wa.y, pp[1]);
            pp[2] = fmaf(mishf(a4[2] + bf2f((unsigned short)hs2a[c]) + bf2f((unsigned short)hr2a[c])), wa.y, pp[2]);
            pp[3] = fmaf(mishf(a4[3] + bf2f((unsigned short)hs3a[c]) + bf2f((unsigned short)hr3a[c])), wa.y, pp[3]);
        }

        bf16x4 hs0b = *(const bf16x4*)(hbf + (size_t)(u0 & 0xFFFFu) * EMB + lanecol * 8 + 4);
        bf16x4 hr0b = *(const bf16x4*)(hbf + (size_t)(u0 >> 16) * EMB + lanecol * 8 + 4);
        bf16x4 hs1b = *(const bf16x4*)(hbf + (size_t)(u1 & 0xFFFFu) * EMB + lanecol * 8 + 4);
        bf16x4 hr1b = *(const bf16x4*)(hbf + (size_t)(u1 >> 16) * EMB + lanecol * 8 + 4);
        bf16x4 hs2b = *(const bf16x4*)(hbf + (size_t)(u2 & 0xFFFFu) * EMB + lanecol * 8 + 4);
        bf16x4 hr2b = *(const bf16x4*)(hbf + (size_t)(u2 >> 16) * EMB + lanecol * 8 + 4);
        bf16x4 hs3b = *(const bf16x4*)(hbf + (size_t)(u3 & 0xFFFFu) * EMB + lanecol * 8 + 4);
        bf16x4 hr3b = *(const bf16x4*)(hbf + (size_t)(u3 >> 16) * EMB + lanecol * 8 + 4);

        #pragma unroll
        for (int c = 4; c < 8; ++c) {
            float2 wa = WA[lanecol * 9 + c];
            bf16x8 b0 = *(bf16x8*)&BHs[(((c << 1) | 0) * 64 + l) * 8];
            bf16x8 b1 = *(bf16x8*)&BHs[(((c << 1) | 1) * 64 + l) * 8];
            f32x4 a4 = (f32x4){wa.x, wa.x, wa.x, wa.x};
            a4 = __builtin_amdgcn_mfma_f32_16x16x32_bf16(ahi0, b0, a4, 0, 0, 0);
            a4 = __builtin_amdgcn_mfma_f32_16x16x32_bf16(ahi1, b1, a4, 0, 0, 0);
            pp[0] = fmaf(mishf(a4[0] + bf2f((unsigned short)hs0b[c - 4]) + bf2f((unsigned short)hr0b[c - 4])), wa.y, pp[0]);
            pp[1] = fmaf(mishf(a4[1] + bf2f((unsigned short)hs1b[c - 4]) + bf2f((unsigned short)hr1b[c - 4])), wa.y, pp[1]);
            pp[2] = fmaf(mishf(a4[2] + bf2f((unsigned short)hs2b[c - 4]) + bf2f((unsigned short)hr2b[c - 4])), wa.y, pp[2]);
            pp[3] = fmaf(mishf(a4[3] + bf2f((unsigned short)hs3b[c - 4]) + bf2f((unsigned short)hr3b[c - 4])), wa.y, pp[3]);
        }

        #pragma unroll
        for (int r = 0; r < 4; ++r) {
            float pr = pp[r];
            pr += __shfl_xor(pr, 1, 16);
            const size_t pos = (size_t)tIdx * 16 + (q << 2) + r;
            if ((lanecol & 1) == 0)
                exbf[pos * NH + (lanecol >> 1)] = rne16(__expf(pr));
        }
    }
}

// --------- segmented aggregation: 16-deep gather burst + 8/4/1 tails -------
__global__ __launch_bounds__(256) void k_agg(
    const short* __restrict__ hbf, const int2* __restrict__ rec,
    const unsigned short* __restrict__ exbf, const int* __restrict__ rowptr,
    float* __restrict__ out) {
    const int l = threadIdx.x & 63;
    const int node = blockIdx.x * 4 + (threadIdx.x >> 6);
    if (node >= NN) return;
    const int beg = rowptr[node], end = rowptr[node + 1];
    const int h = l >> 3;
    float a0 = 0.f, a1 = 0.f, den = 0.f;
    int j = beg;
    for (; j + 16 <= end; j += 16) {
        int s[16];
        float ex[16];
        unsigned hv[16];
        #pragma unroll
        for (int i = 0; i < 16; ++i) s[i] = rec[j + i].y & 0xFFFF;
        #pragma unroll
        for (int i = 0; i < 16; ++i) ex[i] = bf2f(exbf[(size_t)(j + i) * NH + h]);
        #pragma unroll
        for (int i = 0; i < 16; ++i)
            hv[i] = *(const unsigned*)(hbf + (size_t)s[i] * EMB + 2 * l);
        #pragma unroll
        for (int i = 0; i < 16; ++i) {
            a0 = fmaf(ex[i], bf2f((unsigned short)(hv[i] & 0xFFFF)), a0);
            a1 = fmaf(ex[i], bf2f((unsigned short)(hv[i] >> 16)), a1);
            den += ex[i];
        }
    }
    if (j + 8 <= end) {
        int s[8];
        float ex[8];
        unsigned hv[8];
        #pragma unroll
        for (int i = 0; i < 8; ++i) s[i] = rec[j + i].y & 0xFFFF;
        #pragma unroll
        for (int i = 0; i < 8; ++i) ex[i] = bf2f(exbf[(size_t)(j + i) * NH + h]);
        #pragma unroll
        for (int i = 0; i < 8; ++i)
            hv[i] = *(const unsigned*)(hbf + (size_t)s[i] * EMB + 2 * l);
        #pragma unroll
        for (int i = 0; i < 8; ++i) {
            a0 = fmaf(ex[i], bf2f((unsigned short)(hv[i] & 0xFFFF)), a0);
            a1 = fmaf(ex[i], bf2f((unsigned short)(hv[i] >> 16)), a1);
            den += ex[i];
        }
        j += 8;
    }
    if (j + 4 <= end) {
        int s[4];
        float ex[4];
        unsigned hv[4];
        #pragma unroll
        for (int i = 0; i < 4; ++i) s[i] = rec[j + i].y & 0xFFFF;
        #pragma unroll
        for (int i = 0; i < 4; ++i) ex[i] = bf2f(exbf[(size_t)(j + i) * NH + h]);
        #pragma unroll
        for (int i = 0; i < 4; ++i)
            hv[i] = *(const unsigned*)(hbf + (size_t)s[i] * EMB + 2 * l);
        #pragma unroll
        for (int i = 0; i < 4; ++i) {
            a0 = fmaf(ex[i], bf2f((unsigned short)(hv[i] & 0xFFFF)), a0);
            a1 = fmaf(ex[i], bf2f((unsigned short)(hv[i] >> 16)), a1);
            den += ex[i];
        }
        j += 4;
    }
    for (; j < end; ++j) {
        float ex = bf2f(exbf[(size_t)j * NH + h]);
        unsigned hv = *(const unsigned*)(hbf + (size_t)(rec[j].y & 0xFFFF) * EMB + 2 * l);
        a0 = fmaf(ex, bf2f((unsigned short)(hv & 0xFFFF)), a0);
        a1 = fmaf(ex, bf2f((unsigned short)(hv >> 16)), a1);
        den += ex;
    }
    float rd = (end > beg) ? __builtin_amdgcn_rcpf(den) : 0.f;
    float2 o;
    o.x = a0 * rd;
    o.y = a1 * rd;
    *(float2*)&out[(size_t)node * EMB + 2 * l] = o;
}

extern "C" void kernel_launch(void* const* d_in, const int* in_sizes, int n_in,
                              void* d_out, int out_size, void* d_ws, size_t ws_size,
                              hipStream_t stream) {
    const float* X   = (const float*)d_in[0];
    const float* EF  = (const float*)d_in[1];
    const float* W   = (const float*)d_in[2];
    const float* Wb  = (const float*)d_in[3];
    const float* We  = (const float*)d_in[4];
    const float* Web = (const float*)d_in[5];
    const float* Av  = (const float*)d_in[6];
    const int* snd   = (const int*)d_in[7];
    const int* rcv   = (const int*)d_in[8];
    float* out = (float*)d_out;

    char* ws = (char*)d_ws;
    size_t off = 0;
    unsigned short* exbf = (unsigned short*)(ws + off); off += (size_t)NE * NH * 2; // 12.8 MB
    int2* rec     = (int2*)(ws + off);  off += (size_t)NE * 8;         // 6.4 MB
    int* ord      = (int*)(ws + off);   off += (size_t)NE * 4;         // 3.2 MB
    int* rowptr   = (int*)(ws + off);   off += (size_t)(NN + 1) * 4;
    int* cnt      = (int*)(ws + off);   off += (size_t)NN * 4;
    int* part     = (int*)(ws + off);   off += 512;
    short* hbf    = (short*)(ws + off); off += (size_t)NN * EMB * 2;   // 12.8 MB

    hipMemsetAsync(cnt, 0, (size_t)NN * sizeof(int), stream);
    k_proj_hist<<<NPB + NHB, 256, 0, stream>>>(X, W, Wb, hbf, rcv, cnt, ord);
    k_part<<<NB, 512, 0, stream>>>(cnt, rowptr, part);
    k_fix2<<<NB, 512, 0, stream>>>(part, rowptr);
    k_bucket<<<NHB, 256, 0, stream>>>(snd, rcv, ord, rowptr, rec);
    k_edge_attn<<<1792, 256, 0, stream>>>(EF, We, Web, Av, hbf, rec, exbf);
    k_agg<<<(NN + 3) / 4, 256, 0, stream>>>(hbf, rec, exbf, rowptr, out);
}